// Round 9
// baseline (523.422 us; speedup 1.0000x reference)
//
#include <hip/hip_runtime.h>

#define BB 2
#define LL 2048
#define CC 1024
#define HH 16
#define DD 64
#define MM (BB * LL)   // 4096

typedef __bf16 bf16x8 __attribute__((ext_vector_type(8)));
typedef float  f32x4  __attribute__((ext_vector_type(4)));

#define LOG2E 1.44269504088896340736f
// __exp2f collides with glibc's reserved name; prefer the raw v_exp_f32 builtin.
#if defined(__has_builtin)
#if __has_builtin(__builtin_amdgcn_exp2f)
#define EXP2F(x) __builtin_amdgcn_exp2f(x)
#else
#define EXP2F(x) exp2f(x)
#endif
#else
#define EXP2F(x) exp2f(x)
#endif

// ---------------------------------------------------------------------------
// helpers (native bf16 converts: single v_cvt op instead of 4 int ops)
// ---------------------------------------------------------------------------
__device__ __forceinline__ unsigned short f2bf(float x) {
    return __builtin_bit_cast(unsigned short, (__bf16)x);
}
__device__ __forceinline__ void split2(float x, unsigned short& hi, unsigned short& lo) {
    __bf16 h = (__bf16)x;
    hi = __builtin_bit_cast(unsigned short, h);
    lo = __builtin_bit_cast(unsigned short, (__bf16)(x - (float)h));
}

#define GLOAD_LDS16(g, l)                                                      \
    __builtin_amdgcn_global_load_lds(                                          \
        (const __attribute__((address_space(1))) void*)(g),                    \
        (__attribute__((address_space(3))) void*)(l), 16, 0, 0)

#define MFMA16(a, b, c) __builtin_amdgcn_mfma_f32_16x16x32_bf16((a), (b), (c), 0, 0, 0)

// ---------------------------------------------------------------------------
// prep: W [K][N] f32 -> Wt_hi/lo [N][K] bf16 (transpose + split)
// ---------------------------------------------------------------------------
__global__ __launch_bounds__(256) void w_prep(
    const float* __restrict__ W, unsigned short* __restrict__ Whi,
    unsigned short* __restrict__ Wlo)
{
    __shared__ float T[64][65];
    const int tid = threadIdx.x;
    const int k0 = blockIdx.x * 64, n0 = blockIdx.y * 64;
    #pragma unroll
    for (int p = 0; p < 4; ++p) {
        const int idx = tid + p * 256;
        const int r = idx >> 4, c4 = idx & 15;
        float4 v = *(const float4*)&W[(size_t)(k0 + r) * CC + n0 + c4 * 4];
        T[r][c4 * 4 + 0] = v.x; T[r][c4 * 4 + 1] = v.y;
        T[r][c4 * 4 + 2] = v.z; T[r][c4 * 4 + 3] = v.w;
    }
    __syncthreads();
    #pragma unroll
    for (int p = 0; p < 16; ++p) {
        const int idx = tid + p * 256;
        const int n = idx >> 6, k = idx & 63;
        unsigned short hi, lo;
        split2(T[k][n], hi, lo);
        Whi[(size_t)(n0 + n) * CC + k0 + k] = hi;
        Wlo[(size_t)(n0 + n) * CC + k0 + k] = lo;
    }
}

// ---------------------------------------------------------------------------
// prep: X [M][C] f32 -> Xhi/Xlo bf16
// ---------------------------------------------------------------------------
__global__ __launch_bounds__(256) void x_prep(
    const float* __restrict__ X, unsigned short* __restrict__ Xhi,
    unsigned short* __restrict__ Xlo)
{
    const size_t i = (size_t)blockIdx.x * 256 + threadIdx.x;
    float4 v = *(const float4*)&X[i * 4];
    unsigned short h0, l0, h1, l1, h2, l2, h3, l3;
    split2(v.x, h0, l0); split2(v.y, h1, l1);
    split2(v.z, h2, l2); split2(v.w, h3, l3);
    ushort4 hv; hv.x = h0; hv.y = h1; hv.z = h2; hv.w = h3;
    ushort4 lv; lv.x = l0; lv.y = l1; lv.z = l2; lv.w = l3;
    *(ushort4*)&Xhi[i * 4] = hv;
    *(ushort4*)&Xlo[i * 4] = lv;
}

// ---------------------------------------------------------------------------
// prep: Vp f32 [M][C] -> Vt bf16 [B][H][D][L]
// ---------------------------------------------------------------------------
__global__ __launch_bounds__(256) void vt_prep(
    const float* __restrict__ Vp, unsigned short* __restrict__ Vt)
{
    __shared__ float T[64][65];
    const int tid = threadIdx.x;
    const int t = blockIdx.x, h = blockIdx.y, b = blockIdx.z;
    #pragma unroll
    for (int p = 0; p < 4; ++p) {
        const int idx = tid + p * 256;
        const int r = idx >> 4, c4 = idx & 15;
        float4 v = *(const float4*)&Vp[(size_t)(b * LL + t * 64 + r) * CC + h * DD + c4 * 4];
        T[r][c4 * 4 + 0] = v.x; T[r][c4 * 4 + 1] = v.y;
        T[r][c4 * 4 + 2] = v.z; T[r][c4 * 4 + 3] = v.w;
    }
    __syncthreads();
    unsigned short* out = Vt + (size_t)(b * HH + h) * DD * LL;
    #pragma unroll
    for (int p = 0; p < 16; ++p) {
        const int idx = tid + p * 256;
        const int d = idx >> 6, l = idx & 63;
        out[(size_t)d * LL + t * 64 + l] = f2bf(T[l][d]);
    }
}

// ---------------------------------------------------------------------------
// prep: mask int32 [B][1][L][L] -> bit-packed u32 [B][L][L/32]
// ---------------------------------------------------------------------------
__global__ __launch_bounds__(256) void mask_pack(
    const int* __restrict__ mask, unsigned int* __restrict__ mp)
{
    const size_t wi = (size_t)blockIdx.x * 256 + threadIdx.x;
    const int* src = mask + wi * 32;
    unsigned int v = 0;
    #pragma unroll
    for (int j = 0; j < 32; j += 4) {
        int4 m4 = *(const int4*)&src[j];
        if (m4.x != 0) v |= 1u << (j + 0);
        if (m4.y != 0) v |= 1u << (j + 1);
        if (m4.z != 0) v |= 1u << (j + 2);
        if (m4.w != 0) v |= 1u << (j + 3);
    }
    mp[wi] = v;
}

// ---------------------------------------------------------------------------
// split-bf16 GEMM, 2-phase LDS double-buffer (T3-minimum) + k-slot XOR swizzle.
// Y = A[M,K] @ Bt[N,K]^T + bias; Ahi*Bhi + Ahi*Blo + Alo*Bhi.
// 128x128 tile, BK=32, 4 waves (2x2), 4x4 16x16x32 frags per wave.
// Swizzle: 16B k-slot ^= (row>>1)&3 (write: pre-swizzled global src, LDS dest
// linear for global_load_lds; read: same XOR) -> fragment reads are 2-way
// bank-aliased (free) instead of 8-way.
// ---------------------------------------------------------------------------
template <int MODE>
__global__ __launch_bounds__(256) void gemm_split(
    const unsigned short* __restrict__ Ahi, const unsigned short* __restrict__ Alo,
    const unsigned short* __restrict__ Bhi, const unsigned short* __restrict__ Blo,
    const float* __restrict__ bias, float scale,
    float* __restrict__ Yf,
    unsigned short* __restrict__ Yhi, unsigned short* __restrict__ Ylo)
{
    __shared__ __align__(16) unsigned short Ah[2][128 * 32];
    __shared__ __align__(16) unsigned short Al[2][128 * 32];
    __shared__ __align__(16) unsigned short Bh[2][128 * 32];
    __shared__ __align__(16) unsigned short Bl[2][128 * 32];

    const int tid  = threadIdx.x;
    const int lane = tid & 63, w = tid >> 6;
    const int wr = w >> 1, wc = w & 1;
    const int lr = lane & 15, kg = lane >> 4;
    const int row0 = blockIdx.x * 128, col0 = blockIdx.y * 128;

    f32x4 acc[4][4];
    #pragma unroll
    for (int i = 0; i < 4; ++i)
        #pragma unroll
        for (int j = 0; j < 4; ++j)
            acc[i][j] = (f32x4){0.f, 0.f, 0.f, 0.f};

    const int srow = lane >> 2;                              // row in 16-row chunk
    const int ssl  = ((lane & 3) ^ ((srow >> 1) & 3)) * 8;   // swizzled src k-slot (shorts)

    #define GSTAGE(bufi, kt_)                                                  \
        {                                                                      \
            const int k0_ = (kt_) * 32;                                        \
            _Pragma("unroll")                                                  \
            for (int c = 0; c < 2; ++c) {                                      \
                const int chunk = w * 2 + c;                                   \
                const int r = chunk * 16 + srow;                               \
                GLOAD_LDS16(Ahi + (size_t)(row0 + r) * CC + k0_ + ssl, &Ah[bufi][chunk * 512]); \
                GLOAD_LDS16(Alo + (size_t)(row0 + r) * CC + k0_ + ssl, &Al[bufi][chunk * 512]); \
                GLOAD_LDS16(Bhi + (size_t)(col0 + r) * CC + k0_ + ssl, &Bh[bufi][chunk * 512]); \
                GLOAD_LDS16(Blo + (size_t)(col0 + r) * CC + k0_ + ssl, &Bl[bufi][chunk * 512]); \
            }                                                                  \
        }

    GSTAGE(0, 0);
    __syncthreads();                       // tile 0 resident

    const int NT = CC / 32;
    for (int kt = 0; kt < NT; ++kt) {
        const int cur = kt & 1;
        if (kt + 1 < NT) GSTAGE(cur ^ 1, kt + 1);   // async, flies under MFMA

        bf16x8 ah[4], al[4], bh[4], bl[4];
        // read-side XOR: (row>>1)&3 collapses to (lr>>1)&3 (wave/frag offsets
        // are multiples of 16 rows)
        const int ko = (kg ^ ((lr >> 1) & 3)) * 8;
        #pragma unroll
        for (int i = 0; i < 4; ++i) {
            ah[i] = *(const bf16x8*)&Ah[cur][(wr * 64 + i * 16 + lr) * 32 + ko];
            al[i] = *(const bf16x8*)&Al[cur][(wr * 64 + i * 16 + lr) * 32 + ko];
            bh[i] = *(const bf16x8*)&Bh[cur][(wc * 64 + i * 16 + lr) * 32 + ko];
            bl[i] = *(const bf16x8*)&Bl[cur][(wc * 64 + i * 16 + lr) * 32 + ko];
        }
        #pragma unroll
        for (int i = 0; i < 4; ++i)
            #pragma unroll
            for (int j = 0; j < 4; ++j) {
                acc[i][j] = MFMA16(ah[i], bh[j], acc[i][j]);
                acc[i][j] = MFMA16(ah[i], bl[j], acc[i][j]);
                acc[i][j] = MFMA16(al[i], bh[j], acc[i][j]);
            }
        __syncthreads();                   // drains next-tile DMA + read-done
    }
    #undef GSTAGE

    #pragma unroll
    for (int j = 0; j < 4; ++j) {
        const int n = col0 + wc * 64 + j * 16 + lr;
        const float bv = bias[n];
        #pragma unroll
        for (int i = 0; i < 4; ++i) {
            const int mbase = row0 + wr * 64 + i * 16 + kg * 4;
            #pragma unroll
            for (int r = 0; r < 4; ++r) {
                const float v = (acc[i][j][r] + bv) * scale;
                const int m = mbase + r;
                if (MODE == 0) {
                    Yf[(size_t)m * CC + n] = v;
                } else {
                    const int bb = m >> 11, ll = m & (LL - 1);
                    const int hh = n >> 6, dd = n & 63;
                    const size_t o = ((size_t)(bb * HH + hh) * LL + ll) * DD + dd;
                    unsigned short hi, lo;
                    split2(v, hi, lo);
                    Yhi[o] = hi; Ylo[o] = lo;
                }
            }
        }
    }
}

// ---------------------------------------------------------------------------
// flash attention, split-bf16 MFMA, 2-phase K/V double-buffer, exp2 softmax,
// defer-max (THR=8, exact), s_setprio around MFMA clusters (T5).
// Scores arrive pre-scaled by 0.125*log2e.
// ---------------------------------------------------------------------------
__global__ __launch_bounds__(256) void flash_mfma(
    const unsigned short* __restrict__ Qhi, const unsigned short* __restrict__ Qlo,
    const unsigned short* __restrict__ Khi, const unsigned short* __restrict__ Klo,
    const unsigned short* __restrict__ Vt,  const unsigned int* __restrict__ maskp,
    unsigned short* __restrict__ Zhi, unsigned short* __restrict__ Zlo)
{
    __shared__ __align__(16) unsigned short Kh_s[2][64 * 64];
    __shared__ __align__(16) unsigned short Kl_s[2][64 * 64];
    __shared__ __align__(16) unsigned short Vt_s[2][64 * 64];
    __shared__ __align__(16) __bf16 Ps[4][16 * 72];

    const int tid  = threadIdx.x;
    const int lane = tid & 63, w = tid >> 6;
    const int lr = lane & 15, kg = lane >> 4;
    const int q0 = blockIdx.x * 64;
    const int h = blockIdx.y, b = blockIdx.z;
    const size_t bh = (size_t)(b * HH + h);

    const unsigned short* Qhi_b = Qhi + bh * LL * DD;
    const unsigned short* Qlo_b = Qlo + bh * LL * DD;
    const unsigned short* Khi_b = Khi + bh * LL * DD;
    const unsigned short* Klo_b = Klo + bh * LL * DD;
    const unsigned short* Vt_b  = Vt  + bh * DD * LL;

    // resident Q fragments (pre-scaled by 0.125*log2e in Q-GEMM)
    const int qrow = q0 + w * 16 + lr;
    bf16x8 qh[2], ql[2];
    #pragma unroll
    for (int s = 0; s < 2; ++s) {
        qh[s] = *(const bf16x8*)&Qhi_b[(size_t)qrow * DD + s * 32 + kg * 8];
        ql[s] = *(const bf16x8*)&Qlo_b[(size_t)qrow * DD + s * 32 + kg * 8];
    }

    f32x4 oacc[4];
    float m_r[4], l_r[4];
    #pragma unroll
    for (int r = 0; r < 4; ++r) {
        oacc[r] = (f32x4){0.f, 0.f, 0.f, 0.f};
        m_r[r] = -3.0e38f; l_r[r] = 0.f;
    }

    #define FSTAGE(bufi, kt_)                                                  \
        {                                                                      \
            _Pragma("unroll")                                                  \
            for (int c = 0; c < 2; ++c) {                                      \
                const int chunk = w * 2 + c;                                   \
                const int rowi = chunk * 8 + (lane >> 3);                      \
                const int cb   = (lane & 7) * 16;                              \
                const int scb  = cb ^ ((rowi & 7) << 4);                       \
                GLOAD_LDS16(Khi_b + (size_t)((kt_) * 64 + rowi) * DD + scb / 2, &Kh_s[bufi][chunk * 512]); \
                GLOAD_LDS16(Klo_b + (size_t)((kt_) * 64 + rowi) * DD + scb / 2, &Kl_s[bufi][chunk * 512]); \
                GLOAD_LDS16(Vt_b + (size_t)rowi * LL + (kt_) * 64 + scb / 2,    &Vt_s[bufi][chunk * 512]); \
            }                                                                  \
        }

    FSTAGE(0, 0);
    __syncthreads();                       // tile 0 resident

    const int NT = LL / 64;
    for (int kt = 0; kt < NT; ++kt) {
        const int cur = kt & 1;
        if (kt + 1 < NT) FSTAGE(cur ^ 1, kt + 1);   // async under compute

        // S = Q K^T (3-product split), exp2 units
        f32x4 sacc[4];
        #pragma unroll
        for (int j = 0; j < 4; ++j) sacc[j] = (f32x4){0.f, 0.f, 0.f, 0.f};
        __builtin_amdgcn_s_setprio(1);
        #pragma unroll
        for (int j = 0; j < 4; ++j) {
            const int krow = j * 16 + lr;
            const int rswz = (krow & 7) << 4;
            #pragma unroll
            for (int s = 0; s < 2; ++s) {
                const int cb = (s * 64 + kg * 16) ^ rswz;
                bf16x8 kh = *(const bf16x8*)((const char*)&Kh_s[cur][0] + krow * 128 + cb);
                bf16x8 kl = *(const bf16x8*)((const char*)&Kl_s[cur][0] + krow * 128 + cb);
                sacc[j] = MFMA16(qh[s], kh, sacc[j]);
                sacc[j] = MFMA16(qh[s], kl, sacc[j]);
                sacc[j] = MFMA16(ql[s], kh, sacc[j]);
            }
        }
        __builtin_amdgcn_s_setprio(0);

        // mask + per-row tile max
        float mxr[4];
        #pragma unroll
        for (int r = 0; r < 4; ++r) {
            const int qr = q0 + w * 16 + kg * 4 + r;
            const unsigned int* mb = maskp + ((size_t)b * LL + qr) * (LL / 32) + kt * 2;
            const unsigned int m0 = mb[0], m1 = mb[1];
            float mx = -3.0e38f;
            #pragma unroll
            for (int j = 0; j < 4; ++j) {
                const unsigned int wsel = (j < 2) ? m0 : m1;
                const int bit = (j & 1) * 16 + lr;
                if (((wsel >> bit) & 1u) == 0u) sacc[j][r] = -1.0e9f;
                mx = fmaxf(mx, sacc[j][r]);
            }
            #pragma unroll
            for (int off = 1; off < 16; off <<= 1)
                mx = fmaxf(mx, __shfl_xor(mx, off, 16));
            mxr[r] = mx;
        }

        // defer-max: rescale only when some row grows past THR=8 (exact math)
        const float g = fmaxf(fmaxf(mxr[0] - m_r[0], mxr[1] - m_r[1]),
                              fmaxf(mxr[2] - m_r[2], mxr[3] - m_r[3]));
        if (!__all(g <= 8.0f)) {
            #pragma unroll
            for (int r = 0; r < 4; ++r) {
                const float mnew = fmaxf(m_r[r], mxr[r]);
                const float f = EXP2F(m_r[r] - mnew);
                m_r[r] = mnew;
                l_r[r] *= f;
                #pragma unroll
                for (int jd = 0; jd < 4; ++jd) oacc[jd][r] *= f;
            }
        }

        // P = exp2(S - m), row-sum, store bf16 to LDS (per-wave slice)
        #pragma unroll
        for (int r = 0; r < 4; ++r) {
            float sum = 0.f;
            #pragma unroll
            for (int j = 0; j < 4; ++j) {
                const float p = EXP2F(sacc[j][r] - m_r[r]);
                sum += p;
                Ps[w][(kg * 4 + r) * 72 + j * 16 + lr] = (__bf16)p;
            }
            #pragma unroll
            for (int off = 1; off < 16; off <<= 1)
                sum += __shfl_xor(sum, off, 16);
            l_r[r] += sum;
        }
        // per-wave LDS write->read: DS ops from one wave complete in order

        // O += P V
        __builtin_amdgcn_s_setprio(1);
        #pragma unroll
        for (int s = 0; s < 2; ++s) {
            bf16x8 pa = *(const bf16x8*)&Ps[w][lr * 72 + s * 32 + kg * 8];
            #pragma unroll
            for (int jd = 0; jd < 4; ++jd) {
                const int vrow = jd * 16 + lr;
                const int cb = (s * 64 + kg * 16) ^ ((vrow & 7) << 4);
                bf16x8 vb = *(const bf16x8*)((const char*)&Vt_s[cur][0] + vrow * 128 + cb);
                oacc[jd] = MFMA16(pa, vb, oacc[jd]);
            }
        }
        __builtin_amdgcn_s_setprio(0);
        __syncthreads();                   // drains next-tile DMA + read-done
    }
    #undef FSTAGE

    // epilogue: normalize, split, store head-merged [M][C]
    #pragma unroll
    for (int r = 0; r < 4; ++r) {
        const float inv = 1.0f / l_r[r];
        const int qg = q0 + w * 16 + kg * 4 + r;
        const size_t rowb = ((size_t)(b * LL + qg)) * CC + h * DD;
        #pragma unroll
        for (int jd = 0; jd < 4; ++jd) {
            unsigned short hi, lo;
            split2(oacc[jd][r] * inv, hi, lo);
            Zhi[rowb + jd * 16 + lr] = hi;
            Zlo[rowb + jd * 16 + lr] = lo;
        }
    }
}

// ---------------------------------------------------------------------------
extern "C" void kernel_launch(void* const* d_in, const int* in_sizes, int n_in,
                              void* d_out, int out_size, void* d_ws, size_t ws_size,
                              hipStream_t stream)
{
    const float* query = (const float*)d_in[0];
    const float* key   = (const float*)d_in[1];
    const float* value = (const float*)d_in[2];
    const int*   mask  = (const int*)d_in[3];
    const float* WQ = (const float*)d_in[4];
    const float* bQ = (const float*)d_in[5];
    const float* WK = (const float*)d_in[6];
    const float* bK = (const float*)d_in[7];
    const float* WV = (const float*)d_in[8];
    const float* bV = (const float*)d_in[9];
    const float* WO = (const float*)d_in[10];
    const float* bO = (const float*)d_in[11];
    float* out = (float*)d_out;

    char* ws = (char*)d_ws;
    const size_t MB = 1024 * 1024;
    unsigned short* WQt_hi = (unsigned short*)(ws + 0 * MB);
    unsigned short* WQt_lo = (unsigned short*)(ws + 2 * MB);
    unsigned short* WKt_hi = (unsigned short*)(ws + 4 * MB);
    unsigned short* WKt_lo = (unsigned short*)(ws + 6 * MB);
    unsigned short* WVt_hi = (unsigned short*)(ws + 8 * MB);
    unsigned short* WVt_lo = (unsigned short*)(ws + 10 * MB);
    unsigned short* WOt_hi = (unsigned short*)(ws + 12 * MB);
    unsigned short* WOt_lo = (unsigned short*)(ws + 14 * MB);
    unsigned short* Xhi    = (unsigned short*)(ws + 16 * MB);  // reused q,k,v; then Zh
    unsigned short* Xlo    = (unsigned short*)(ws + 24 * MB);
    unsigned short* Qh_hi  = (unsigned short*)(ws + 32 * MB);
    unsigned short* Qh_lo  = (unsigned short*)(ws + 40 * MB);
    unsigned short* Kh_hi  = (unsigned short*)(ws + 48 * MB);
    unsigned short* Kh_lo  = (unsigned short*)(ws + 56 * MB);
    float*          Vp     = (float*)(ws + 64 * MB);
    unsigned short* Vt     = (unsigned short*)(ws + 80 * MB);
    unsigned int*   maskp  = (unsigned int*)(ws + 88 * MB);    // total 90 MB

    const dim3 blk(256);
    const dim3 wgrid(CC / 64, CC / 64);
    w_prep<<<wgrid, blk, 0, stream>>>(WQ, WQt_hi, WQt_lo);
    w_prep<<<wgrid, blk, 0, stream>>>(WK, WKt_hi, WKt_lo);
    w_prep<<<wgrid, blk, 0, stream>>>(WV, WVt_hi, WVt_lo);
    w_prep<<<wgrid, blk, 0, stream>>>(WO, WOt_hi, WOt_lo);
    mask_pack<<<dim3((BB * LL * (LL / 32)) / 256), blk, 0, stream>>>(mask, maskp);

    const dim3 ggrid(MM / 128, CC / 128);
    const dim3 xgrid((size_t)MM * CC / 4 / 256);

    // Q = (query @ WQ + bQ) * 0.125*log2e  -> split head layout (exp2 units)
    x_prep<<<xgrid, blk, 0, stream>>>(query, Xhi, Xlo);
    gemm_split<1><<<ggrid, blk, 0, stream>>>(Xhi, Xlo, WQt_hi, WQt_lo, bQ,
                                             0.125f * LOG2E, nullptr, Qh_hi, Qh_lo);
    // K -> split head layout
    x_prep<<<xgrid, blk, 0, stream>>>(key, Xhi, Xlo);
    gemm_split<1><<<ggrid, blk, 0, stream>>>(Xhi, Xlo, WKt_hi, WKt_lo, bK, 1.0f,
                                             nullptr, Kh_hi, Kh_lo);
    // V -> f32, then transpose to [B][H][D][L] bf16
    x_prep<<<xgrid, blk, 0, stream>>>(value, Xhi, Xlo);
    gemm_split<0><<<ggrid, blk, 0, stream>>>(Xhi, Xlo, WVt_hi, WVt_lo, bV, 1.0f,
                                             Vp, nullptr, nullptr);
    vt_prep<<<dim3(LL / 64, HH, BB), blk, 0, stream>>>(Vp, Vt);

    // attention -> Zh (split, reuses X buffers)
    flash_mfma<<<dim3(LL / 64, HH, BB), blk, 0, stream>>>(
        Qh_hi, Qh_lo, Kh_hi, Kh_lo, Vt, maskp, Xhi, Xlo);

    // out = Zh @ WO + bO
    gemm_split<0><<<ggrid, blk, 0, stream>>>(Xhi, Xlo, WOt_hi, WOt_lo, bO, 1.0f,
                                             out, nullptr, nullptr);
}

// Round 10
// 483.914 us; speedup vs baseline: 1.0816x; 1.0816x over previous
//
#include <hip/hip_runtime.h>

#define BB 2
#define LL 2048
#define CC 1024
#define HH 16
#define DD 64
#define MM (BB * LL)   // 4096

typedef __bf16 bf16x8 __attribute__((ext_vector_type(8)));
typedef float  f32x4  __attribute__((ext_vector_type(4)));

#define LOG2E 1.44269504088896340736f
// __exp2f collides with glibc's reserved name; prefer the raw v_exp_f32 builtin.
#if defined(__has_builtin)
#if __has_builtin(__builtin_amdgcn_exp2f)
#define EXP2F(x) __builtin_amdgcn_exp2f(x)
#else
#define EXP2F(x) exp2f(x)
#endif
#else
#define EXP2F(x) exp2f(x)
#endif

// ---------------------------------------------------------------------------
// helpers
// ---------------------------------------------------------------------------
__device__ __forceinline__ unsigned short f2bf(float x) {
    return __builtin_bit_cast(unsigned short, (__bf16)x);
}
__device__ __forceinline__ void split2(float x, unsigned short& hi, unsigned short& lo) {
    __bf16 h = (__bf16)x;
    hi = __builtin_bit_cast(unsigned short, h);
    lo = __builtin_bit_cast(unsigned short, (__bf16)(x - (float)h));
}

#define GLOAD_LDS16(g, l)                                                      \
    __builtin_amdgcn_global_load_lds(                                          \
        (const __attribute__((address_space(1))) void*)(g),                    \
        (__attribute__((address_space(3))) void*)(l), 16, 0, 0)

#define MFMA16(a, b, c) __builtin_amdgcn_mfma_f32_16x16x32_bf16((a), (b), (c), 0, 0, 0)

// ---------------------------------------------------------------------------
// prep: W [K][N] f32 -> Wt_hi/lo [N][K] bf16 (transpose + split)
// ---------------------------------------------------------------------------
__global__ __launch_bounds__(256) void w_prep(
    const float* __restrict__ W, unsigned short* __restrict__ Whi,
    unsigned short* __restrict__ Wlo)
{
    __shared__ float T[64][65];
    const int tid = threadIdx.x;
    const int k0 = blockIdx.x * 64, n0 = blockIdx.y * 64;
    #pragma unroll
    for (int p = 0; p < 4; ++p) {
        const int idx = tid + p * 256;
        const int r = idx >> 4, c4 = idx & 15;
        float4 v = *(const float4*)&W[(size_t)(k0 + r) * CC + n0 + c4 * 4];
        T[r][c4 * 4 + 0] = v.x; T[r][c4 * 4 + 1] = v.y;
        T[r][c4 * 4 + 2] = v.z; T[r][c4 * 4 + 3] = v.w;
    }
    __syncthreads();
    #pragma unroll
    for (int p = 0; p < 16; ++p) {
        const int idx = tid + p * 256;
        const int n = idx >> 6, k = idx & 63;
        unsigned short hi, lo;
        split2(T[k][n], hi, lo);
        Whi[(size_t)(n0 + n) * CC + k0 + k] = hi;
        Wlo[(size_t)(n0 + n) * CC + k0 + k] = lo;
    }
}

// ---------------------------------------------------------------------------
// prep: X [M][C] f32 -> Xhi/Xlo bf16
// ---------------------------------------------------------------------------
__global__ __launch_bounds__(256) void x_prep(
    const float* __restrict__ X, unsigned short* __restrict__ Xhi,
    unsigned short* __restrict__ Xlo)
{
    const size_t i = (size_t)blockIdx.x * 256 + threadIdx.x;
    float4 v = *(const float4*)&X[i * 4];
    unsigned short h0, l0, h1, l1, h2, l2, h3, l3;
    split2(v.x, h0, l0); split2(v.y, h1, l1);
    split2(v.z, h2, l2); split2(v.w, h3, l3);
    ushort4 hv; hv.x = h0; hv.y = h1; hv.z = h2; hv.w = h3;
    ushort4 lv; lv.x = l0; lv.y = l1; lv.z = l2; lv.w = l3;
    *(ushort4*)&Xhi[i * 4] = hv;
    *(ushort4*)&Xlo[i * 4] = lv;
}

// ---------------------------------------------------------------------------
// prep: Vp f32 [M][C] -> Vt bf16 [B][H][D][L]
// ---------------------------------------------------------------------------
__global__ __launch_bounds__(256) void vt_prep(
    const float* __restrict__ Vp, unsigned short* __restrict__ Vt)
{
    __shared__ float T[64][65];
    const int tid = threadIdx.x;
    const int t = blockIdx.x, h = blockIdx.y, b = blockIdx.z;
    #pragma unroll
    for (int p = 0; p < 4; ++p) {
        const int idx = tid + p * 256;
        const int r = idx >> 4, c4 = idx & 15;
        float4 v = *(const float4*)&Vp[(size_t)(b * LL + t * 64 + r) * CC + h * DD + c4 * 4];
        T[r][c4 * 4 + 0] = v.x; T[r][c4 * 4 + 1] = v.y;
        T[r][c4 * 4 + 2] = v.z; T[r][c4 * 4 + 3] = v.w;
    }
    __syncthreads();
    unsigned short* out = Vt + (size_t)(b * HH + h) * DD * LL;
    #pragma unroll
    for (int p = 0; p < 16; ++p) {
        const int idx = tid + p * 256;
        const int d = idx >> 6, l = idx & 63;
        out[(size_t)d * LL + t * 64 + l] = f2bf(T[l][d]);
    }
}

// ---------------------------------------------------------------------------
// prep: mask int32 [B][1][L][L] -> bit-packed u32 [B][L][L/32]
// ---------------------------------------------------------------------------
__global__ __launch_bounds__(256) void mask_pack(
    const int* __restrict__ mask, unsigned int* __restrict__ mp)
{
    const size_t wi = (size_t)blockIdx.x * 256 + threadIdx.x;
    const int* src = mask + wi * 32;
    unsigned int v = 0;
    #pragma unroll
    for (int j = 0; j < 32; j += 4) {
        int4 m4 = *(const int4*)&src[j];
        if (m4.x != 0) v |= 1u << (j + 0);
        if (m4.y != 0) v |= 1u << (j + 1);
        if (m4.z != 0) v |= 1u << (j + 2);
        if (m4.w != 0) v |= 1u << (j + 3);
    }
    mp[wi] = v;
}

// ---------------------------------------------------------------------------
// split-bf16 GEMM, single-buffer (m97-style 2-barrier K-loop, 32KB LDS ->
// 4-5 blocks/CU; round-9 showed dbuf's 64KB halves occupancy for no gain)
// + k-slot XOR swizzle (8-way -> 2-way bank conflict on fragment reads).
// Y = A[M,K] @ Bt[N,K]^T + bias; Ahi*Bhi + Ahi*Blo + Alo*Bhi.
// 128x128 tile, BK=32, 4 waves (2x2), 4x4 16x16x32 frags per wave.
// ---------------------------------------------------------------------------
template <int MODE>
__global__ __launch_bounds__(256) void gemm_split(
    const unsigned short* __restrict__ Ahi, const unsigned short* __restrict__ Alo,
    const unsigned short* __restrict__ Bhi, const unsigned short* __restrict__ Blo,
    const float* __restrict__ bias, float scale,
    float* __restrict__ Yf,
    unsigned short* __restrict__ Yhi, unsigned short* __restrict__ Ylo)
{
    __shared__ __align__(16) unsigned short Ah[128 * 32];
    __shared__ __align__(16) unsigned short Al[128 * 32];
    __shared__ __align__(16) unsigned short Bh[128 * 32];
    __shared__ __align__(16) unsigned short Bl[128 * 32];

    const int tid  = threadIdx.x;
    const int lane = tid & 63, w = tid >> 6;
    const int wr = w >> 1, wc = w & 1;
    const int lr = lane & 15, kg = lane >> 4;
    const int row0 = blockIdx.x * 128, col0 = blockIdx.y * 128;

    f32x4 acc[4][4];
    #pragma unroll
    for (int i = 0; i < 4; ++i)
        #pragma unroll
        for (int j = 0; j < 4; ++j)
            acc[i][j] = (f32x4){0.f, 0.f, 0.f, 0.f};

    const int srow = lane >> 2;                              // row in 16-row chunk
    const int ssl  = ((lane & 3) ^ ((srow >> 1) & 3)) * 8;   // swizzled src k-slot (shorts)
    // read-side XOR: (row>>1)&3 collapses to (lr>>1)&3 (frag rows = 16m+lr)
    const int ko   = (kg ^ ((lr >> 1) & 3)) * 8;

    const int NT = CC / 32;
    for (int kt = 0; kt < NT; ++kt) {
        const int k0 = kt * 32;
        #pragma unroll
        for (int c = 0; c < 2; ++c) {
            const int chunk = w * 2 + c;                     // 0..7 -> 16 rows each
            const int r = chunk * 16 + srow;
            GLOAD_LDS16(Ahi + (size_t)(row0 + r) * CC + k0 + ssl, &Ah[chunk * 512]);
            GLOAD_LDS16(Alo + (size_t)(row0 + r) * CC + k0 + ssl, &Al[chunk * 512]);
            GLOAD_LDS16(Bhi + (size_t)(col0 + r) * CC + k0 + ssl, &Bh[chunk * 512]);
            GLOAD_LDS16(Blo + (size_t)(col0 + r) * CC + k0 + ssl, &Bl[chunk * 512]);
        }
        __syncthreads();                   // drains DMA; tile resident

        bf16x8 ah[4], al[4], bh[4], bl[4];
        #pragma unroll
        for (int i = 0; i < 4; ++i) {
            ah[i] = *(const bf16x8*)&Ah[(wr * 64 + i * 16 + lr) * 32 + ko];
            al[i] = *(const bf16x8*)&Al[(wr * 64 + i * 16 + lr) * 32 + ko];
            bh[i] = *(const bf16x8*)&Bh[(wc * 64 + i * 16 + lr) * 32 + ko];
            bl[i] = *(const bf16x8*)&Bl[(wc * 64 + i * 16 + lr) * 32 + ko];
        }
        #pragma unroll
        for (int i = 0; i < 4; ++i)
            #pragma unroll
            for (int j = 0; j < 4; ++j) {
                acc[i][j] = MFMA16(ah[i], bh[j], acc[i][j]);
                acc[i][j] = MFMA16(ah[i], bl[j], acc[i][j]);
                acc[i][j] = MFMA16(al[i], bh[j], acc[i][j]);
            }
        __syncthreads();                   // all reads done before next stage
    }

    #pragma unroll
    for (int j = 0; j < 4; ++j) {
        const int n = col0 + wc * 64 + j * 16 + lr;
        const float bv = bias[n];
        #pragma unroll
        for (int i = 0; i < 4; ++i) {
            const int mbase = row0 + wr * 64 + i * 16 + kg * 4;
            #pragma unroll
            for (int r = 0; r < 4; ++r) {
                const float v = (acc[i][j][r] + bv) * scale;
                const int m = mbase + r;
                if (MODE == 0) {
                    Yf[(size_t)m * CC + n] = v;
                } else {
                    const int bb = m >> 11, ll = m & (LL - 1);
                    const int hh = n >> 6, dd = n & 63;
                    const size_t o = ((size_t)(bb * HH + hh) * LL + ll) * DD + dd;
                    unsigned short hi, lo;
                    split2(v, hi, lo);
                    Yhi[o] = hi; Ylo[o] = lo;
                }
            }
        }
    }
}

// ---------------------------------------------------------------------------
// flash attention, split-bf16 MFMA, single-buffer K/V (33KB LDS -> 4 blocks/CU;
// round-9 dbuf at 58KB halved occupancy and was net-negative), exp2 softmax,
// defer-max (THR=8, exact), s_setprio around MFMA clusters (T5).
// Scores arrive pre-scaled by 0.125*log2e.
// ---------------------------------------------------------------------------
__global__ __launch_bounds__(256) void flash_mfma(
    const unsigned short* __restrict__ Qhi, const unsigned short* __restrict__ Qlo,
    const unsigned short* __restrict__ Khi, const unsigned short* __restrict__ Klo,
    const unsigned short* __restrict__ Vt,  const unsigned int* __restrict__ maskp,
    unsigned short* __restrict__ Zhi, unsigned short* __restrict__ Zlo)
{
    __shared__ __align__(16) unsigned short Kh_s[64 * 64];
    __shared__ __align__(16) unsigned short Kl_s[64 * 64];
    __shared__ __align__(16) unsigned short Vt_s[64 * 64];
    __shared__ __align__(16) __bf16 Ps[4][16 * 72];

    const int tid  = threadIdx.x;
    const int lane = tid & 63, w = tid >> 6;
    const int lr = lane & 15, kg = lane >> 4;
    const int q0 = blockIdx.x * 64;
    const int h = blockIdx.y, b = blockIdx.z;
    const size_t bh = (size_t)(b * HH + h);

    const unsigned short* Qhi_b = Qhi + bh * LL * DD;
    const unsigned short* Qlo_b = Qlo + bh * LL * DD;
    const unsigned short* Khi_b = Khi + bh * LL * DD;
    const unsigned short* Klo_b = Klo + bh * LL * DD;
    const unsigned short* Vt_b  = Vt  + bh * DD * LL;

    // resident Q fragments (pre-scaled by 0.125*log2e in Q-GEMM)
    const int qrow = q0 + w * 16 + lr;
    bf16x8 qh[2], ql[2];
    #pragma unroll
    for (int s = 0; s < 2; ++s) {
        qh[s] = *(const bf16x8*)&Qhi_b[(size_t)qrow * DD + s * 32 + kg * 8];
        ql[s] = *(const bf16x8*)&Qlo_b[(size_t)qrow * DD + s * 32 + kg * 8];
    }

    f32x4 oacc[4];
    float m_r[4], l_r[4];
    #pragma unroll
    for (int r = 0; r < 4; ++r) {
        oacc[r] = (f32x4){0.f, 0.f, 0.f, 0.f};
        m_r[r] = -3.0e38f; l_r[r] = 0.f;
    }

    const int NT = LL / 64;
    for (int kt = 0; kt < NT; ++kt) {
        // stage K hi/lo + V^T: linear LDS dest, pre-swizzled global source
        #pragma unroll
        for (int c = 0; c < 2; ++c) {
            const int chunk = w * 2 + c;                  // 0..7, 8 rows each
            const int rowi = chunk * 8 + (lane >> 3);
            const int cb   = (lane & 7) * 16;             // dest col-byte
            const int scb  = cb ^ ((rowi & 7) << 4);      // source col-byte
            GLOAD_LDS16(Khi_b + (size_t)(kt * 64 + rowi) * DD + scb / 2, &Kh_s[chunk * 512]);
            GLOAD_LDS16(Klo_b + (size_t)(kt * 64 + rowi) * DD + scb / 2, &Kl_s[chunk * 512]);
            GLOAD_LDS16(Vt_b + (size_t)rowi * LL + kt * 64 + scb / 2,    &Vt_s[chunk * 512]);
        }
        __syncthreads();                   // tile resident

        // S = Q K^T (3-product split), exp2 units
        f32x4 sacc[4];
        #pragma unroll
        for (int j = 0; j < 4; ++j) sacc[j] = (f32x4){0.f, 0.f, 0.f, 0.f};
        __builtin_amdgcn_s_setprio(1);
        #pragma unroll
        for (int j = 0; j < 4; ++j) {
            const int krow = j * 16 + lr;
            const int rswz = (krow & 7) << 4;
            #pragma unroll
            for (int s = 0; s < 2; ++s) {
                const int cb = (s * 64 + kg * 16) ^ rswz;
                bf16x8 kh = *(const bf16x8*)((const char*)&Kh_s[0] + krow * 128 + cb);
                bf16x8 kl = *(const bf16x8*)((const char*)&Kl_s[0] + krow * 128 + cb);
                sacc[j] = MFMA16(qh[s], kh, sacc[j]);
                sacc[j] = MFMA16(qh[s], kl, sacc[j]);
                sacc[j] = MFMA16(ql[s], kh, sacc[j]);
            }
        }
        __builtin_amdgcn_s_setprio(0);

        // mask + per-row tile max
        float mxr[4];
        #pragma unroll
        for (int r = 0; r < 4; ++r) {
            const int qr = q0 + w * 16 + kg * 4 + r;
            const unsigned int* mb = maskp + ((size_t)b * LL + qr) * (LL / 32) + kt * 2;
            const unsigned int m0 = mb[0], m1 = mb[1];
            float mx = -3.0e38f;
            #pragma unroll
            for (int j = 0; j < 4; ++j) {
                const unsigned int wsel = (j < 2) ? m0 : m1;
                const int bit = (j & 1) * 16 + lr;
                if (((wsel >> bit) & 1u) == 0u) sacc[j][r] = -1.0e9f;
                mx = fmaxf(mx, sacc[j][r]);
            }
            #pragma unroll
            for (int off = 1; off < 16; off <<= 1)
                mx = fmaxf(mx, __shfl_xor(mx, off, 16));
            mxr[r] = mx;
        }

        // defer-max: rescale only when some row grows past THR=8 (exact math)
        const float g = fmaxf(fmaxf(mxr[0] - m_r[0], mxr[1] - m_r[1]),
                              fmaxf(mxr[2] - m_r[2], mxr[3] - m_r[3]));
        if (!__all(g <= 8.0f)) {
            #pragma unroll
            for (int r = 0; r < 4; ++r) {
                const float mnew = fmaxf(m_r[r], mxr[r]);
                const float f = EXP2F(m_r[r] - mnew);
                m_r[r] = mnew;
                l_r[r] *= f;
                #pragma unroll
                for (int jd = 0; jd < 4; ++jd) oacc[jd][r] *= f;
            }
        }

        // P = exp2(S - m), row-sum, store bf16 to LDS (per-wave slice)
        #pragma unroll
        for (int r = 0; r < 4; ++r) {
            float sum = 0.f;
            #pragma unroll
            for (int j = 0; j < 4; ++j) {
                const float p = EXP2F(sacc[j][r] - m_r[r]);
                sum += p;
                Ps[w][(kg * 4 + r) * 72 + j * 16 + lr] = (__bf16)p;
            }
            #pragma unroll
            for (int off = 1; off < 16; off <<= 1)
                sum += __shfl_xor(sum, off, 16);
            l_r[r] += sum;
        }
        // per-wave LDS write->read: DS ops from one wave complete in order

        // O += P V
        __builtin_amdgcn_s_setprio(1);
        #pragma unroll
        for (int s = 0; s < 2; ++s) {
            bf16x8 pa = *(const bf16x8*)&Ps[w][lr * 72 + s * 32 + kg * 8];
            #pragma unroll
            for (int jd = 0; jd < 4; ++jd) {
                const int vrow = jd * 16 + lr;
                const int cb = (s * 64 + kg * 16) ^ ((vrow & 7) << 4);
                bf16x8 vb = *(const bf16x8*)((const char*)&Vt_s[0] + vrow * 128 + cb);
                oacc[jd] = MFMA16(pa, vb, oacc[jd]);
            }
        }
        __builtin_amdgcn_s_setprio(0);
        __syncthreads();                   // all K/V reads done before next stage
    }

    // epilogue: normalize, split, store head-merged [M][C]
    #pragma unroll
    for (int r = 0; r < 4; ++r) {
        const float inv = 1.0f / l_r[r];
        const int qg = q0 + w * 16 + kg * 4 + r;
        const size_t rowb = ((size_t)(b * LL + qg)) * CC + h * DD;
        #pragma unroll
        for (int jd = 0; jd < 4; ++jd) {
            unsigned short hi, lo;
            split2(oacc[jd][r] * inv, hi, lo);
            Zhi[rowb + jd * 16 + lr] = hi;
            Zlo[rowb + jd * 16 + lr] = lo;
        }
    }
}

// ---------------------------------------------------------------------------
extern "C" void kernel_launch(void* const* d_in, const int* in_sizes, int n_in,
                              void* d_out, int out_size, void* d_ws, size_t ws_size,
                              hipStream_t stream)
{
    const float* query = (const float*)d_in[0];
    const float* key   = (const float*)d_in[1];
    const float* value = (const float*)d_in[2];
    const int*   mask  = (const int*)d_in[3];
    const float* WQ = (const float*)d_in[4];
    const float* bQ = (const float*)d_in[5];
    const float* WK = (const float*)d_in[6];
    const float* bK = (const float*)d_in[7];
    const float* WV = (const float*)d_in[8];
    const float* bV = (const float*)d_in[9];
    const float* WO = (const float*)d_in[10];
    const float* bO = (const float*)d_in[11];
    float* out = (float*)d_out;

    char* ws = (char*)d_ws;
    const size_t MB = 1024 * 1024;
    unsigned short* WQt_hi = (unsigned short*)(ws + 0 * MB);
    unsigned short* WQt_lo = (unsigned short*)(ws + 2 * MB);
    unsigned short* WKt_hi = (unsigned short*)(ws + 4 * MB);
    unsigned short* WKt_lo = (unsigned short*)(ws + 6 * MB);
    unsigned short* WVt_hi = (unsigned short*)(ws + 8 * MB);
    unsigned short* WVt_lo = (unsigned short*)(ws + 10 * MB);
    unsigned short* WOt_hi = (unsigned short*)(ws + 12 * MB);
    unsigned short* WOt_lo = (unsigned short*)(ws + 14 * MB);
    unsigned short* Xhi    = (unsigned short*)(ws + 16 * MB);  // reused q,k,v; then Zh
    unsigned short* Xlo    = (unsigned short*)(ws + 24 * MB);
    unsigned short* Qh_hi  = (unsigned short*)(ws + 32 * MB);
    unsigned short* Qh_lo  = (unsigned short*)(ws + 40 * MB);
    unsigned short* Kh_hi  = (unsigned short*)(ws + 48 * MB);
    unsigned short* Kh_lo  = (unsigned short*)(ws + 56 * MB);
    float*          Vp     = (float*)(ws + 64 * MB);
    unsigned short* Vt     = (unsigned short*)(ws + 80 * MB);
    unsigned int*   maskp  = (unsigned int*)(ws + 88 * MB);    // total 90 MB

    const dim3 blk(256);
    const dim3 wgrid(CC / 64, CC / 64);
    w_prep<<<wgrid, blk, 0, stream>>>(WQ, WQt_hi, WQt_lo);
    w_prep<<<wgrid, blk, 0, stream>>>(WK, WKt_hi, WKt_lo);
    w_prep<<<wgrid, blk, 0, stream>>>(WV, WVt_hi, WVt_lo);
    w_prep<<<wgrid, blk, 0, stream>>>(WO, WOt_hi, WOt_lo);
    mask_pack<<<dim3((BB * LL * (LL / 32)) / 256), blk, 0, stream>>>(mask, maskp);

    const dim3 ggrid(MM / 128, CC / 128);
    const dim3 xgrid((size_t)MM * CC / 4 / 256);

    // Q = (query @ WQ + bQ) * 0.125*log2e  -> split head layout (exp2 units)
    x_prep<<<xgrid, blk, 0, stream>>>(query, Xhi, Xlo);
    gemm_split<1><<<ggrid, blk, 0, stream>>>(Xhi, Xlo, WQt_hi, WQt_lo, bQ,
                                             0.125f * LOG2E, nullptr, Qh_hi, Qh_lo);
    // K -> split head layout
    x_prep<<<xgrid, blk, 0, stream>>>(key, Xhi, Xlo);
    gemm_split<1><<<ggrid, blk, 0, stream>>>(Xhi, Xlo, WKt_hi, WKt_lo, bK, 1.0f,
                                             nullptr, Kh_hi, Kh_lo);
    // V -> f32, then transpose to [B][H][D][L] bf16
    x_prep<<<xgrid, blk, 0, stream>>>(value, Xhi, Xlo);
    gemm_split<0><<<ggrid, blk, 0, stream>>>(Xhi, Xlo, WVt_hi, WVt_lo, bV, 1.0f,
                                             Vp, nullptr, nullptr);
    vt_prep<<<dim3(LL / 64, HH, BB), blk, 0, stream>>>(Vp, Vt);

    // attention -> Zh (split, reuses X buffers)
    flash_mfma<<<dim3(LL / 64, HH, BB), blk, 0, stream>>>(
        Qh_hi, Qh_lo, Kh_hi, Kh_lo, Vt, maskp, Xhi, Xlo);

    // out = Zh @ WO + bO
    gemm_split<0><<<ggrid, blk, 0, stream>>>(Xhi, Xlo, WOt_hi, WOt_lo, bO, 1.0f,
                                             out, nullptr, nullptr);
}

// Round 11
// 423.017 us; speedup vs baseline: 1.2374x; 1.1440x over previous
//
#include <hip/hip_runtime.h>

#define BB 2
#define LL 2048
#define CC 1024
#define HH 16
#define DD 64
#define MM (BB * LL)   // 4096

typedef __bf16 bf16x8 __attribute__((ext_vector_type(8)));
typedef float  f32x4  __attribute__((ext_vector_type(4)));

#define LOG2E 1.44269504088896340736f
#if defined(__has_builtin)
#if __has_builtin(__builtin_amdgcn_exp2f)
#define EXP2F(x) __builtin_amdgcn_exp2f(x)
#else
#define EXP2F(x) exp2f(x)
#endif
#else
#define EXP2F(x) exp2f(x)
#endif

__device__ __forceinline__ unsigned short f2bf(float x) {
    return __builtin_bit_cast(unsigned short, (__bf16)x);
}
__device__ __forceinline__ void split2(float x, unsigned short& hi, unsigned short& lo) {
    __bf16 h = (__bf16)x;
    hi = __builtin_bit_cast(unsigned short, h);
    lo = __builtin_bit_cast(unsigned short, (__bf16)(x - (float)h));
}

#define GLOAD_LDS16(g, l)                                                      \
    __builtin_amdgcn_global_load_lds(                                          \
        (const __attribute__((address_space(1))) void*)(g),                    \
        (__attribute__((address_space(3))) void*)(l), 16, 0, 0)

#define MFMA16(a, b, c) __builtin_amdgcn_mfma_f32_16x16x32_bf16((a), (b), (c), 0, 0, 0)

// ---------------------------------------------------------------------------
// prep: 4 weights in one launch. W [K][N] f32 -> Wt hi/lo [N][K] bf16.
// grid (16, 16, 4)
// ---------------------------------------------------------------------------
__global__ __launch_bounds__(256) void w_prep4(
    const float* __restrict__ WQ, const float* __restrict__ WK,
    const float* __restrict__ WV, const float* __restrict__ WO,
    char* __restrict__ wsbase)
{
    __shared__ float T[64][65];
    const int tid = threadIdx.x;
    const int k0 = blockIdx.x * 64, n0 = blockIdx.y * 64;
    const int z = blockIdx.z;
    const float* W = (z == 0) ? WQ : (z == 1) ? WK : (z == 2) ? WV : WO;
    unsigned short* Whi = (unsigned short*)(wsbase + (size_t)z * 4 * 1024 * 1024);
    unsigned short* Wlo = Whi + (size_t)CC * CC;

    #pragma unroll
    for (int p = 0; p < 4; ++p) {
        const int idx = tid + p * 256;
        const int r = idx >> 4, c4 = idx & 15;
        float4 v = *(const float4*)&W[(size_t)(k0 + r) * CC + n0 + c4 * 4];
        T[r][c4 * 4 + 0] = v.x; T[r][c4 * 4 + 1] = v.y;
        T[r][c4 * 4 + 2] = v.z; T[r][c4 * 4 + 3] = v.w;
    }
    __syncthreads();
    #pragma unroll
    for (int p = 0; p < 16; ++p) {
        const int idx = tid + p * 256;
        const int n = idx >> 6, k = idx & 63;
        unsigned short hi, lo;
        split2(T[k][n], hi, lo);
        Whi[(size_t)(n0 + n) * CC + k0 + k] = hi;
        Wlo[(size_t)(n0 + n) * CC + k0 + k] = lo;
    }
}

// ---------------------------------------------------------------------------
// prep: query/key/value -> concatenated Xall hi/lo [3*M][C] bf16.
// grid (M*C/4/256, 3)
// ---------------------------------------------------------------------------
__global__ __launch_bounds__(256) void x_prep3(
    const float* __restrict__ query, const float* __restrict__ key,
    const float* __restrict__ value,
    unsigned short* __restrict__ Xhi, unsigned short* __restrict__ Xlo)
{
    const int y = blockIdx.y;
    const float* src = (y == 0) ? query : (y == 1) ? key : value;
    const size_t i = (size_t)blockIdx.x * 256 + threadIdx.x;   // float4 idx
    const size_t o = (size_t)y * MM * CC + i * 4;
    float4 v = *(const float4*)&src[i * 4];
    unsigned short h0, l0, h1, l1, h2, l2, h3, l3;
    split2(v.x, h0, l0); split2(v.y, h1, l1);
    split2(v.z, h2, l2); split2(v.w, h3, l3);
    ushort4 hv; hv.x = h0; hv.y = h1; hv.z = h2; hv.w = h3;
    ushort4 lv; lv.x = l0; lv.y = l1; lv.z = l2; lv.w = l3;
    *(ushort4*)&Xhi[o] = hv;
    *(ushort4*)&Xlo[o] = lv;
}

// ---------------------------------------------------------------------------
// prep: mask int32 [B][1][L][L] -> bit-packed u32 [B][L][L/32]
// ---------------------------------------------------------------------------
__global__ __launch_bounds__(256) void mask_pack(
    const int* __restrict__ mask, unsigned int* __restrict__ mp)
{
    const size_t wi = (size_t)blockIdx.x * 256 + threadIdx.x;
    const int* src = mask + wi * 32;
    unsigned int v = 0;
    #pragma unroll
    for (int j = 0; j < 32; j += 4) {
        int4 m4 = *(const int4*)&src[j];
        if (m4.x != 0) v |= 1u << (j + 0);
        if (m4.y != 0) v |= 1u << (j + 1);
        if (m4.z != 0) v |= 1u << (j + 2);
        if (m4.w != 0) v |= 1u << (j + 3);
    }
    mp[wi] = v;
}

// ---------------------------------------------------------------------------
// batched Q/K/V split-bf16 GEMM over A=[3M][C]: 768 blocks = 3 blocks/CU
// (round-10 GEMMs ran 256 blocks = 1 wave/SIMD: latency-exposed, 15% util).
// 128x128 tile, BK=32, single-buffer, k-slot XOR swizzle.
// sel 0: Q -> split head layout, scale 0.125*log2e; sel 1: K -> split head
// layout; sel 2: V -> plain bf16 TRANSPOSED [B][H][D][L] (replaces vt_prep).
// ---------------------------------------------------------------------------
__global__ __launch_bounds__(256) void qkv_gemm(
    const unsigned short* __restrict__ Ahi, const unsigned short* __restrict__ Alo,
    const unsigned short* __restrict__ WQt_hi, const unsigned short* __restrict__ WKt_hi,
    const unsigned short* __restrict__ WVt_hi,
    const float* __restrict__ bQ, const float* __restrict__ bK,
    const float* __restrict__ bV,
    unsigned short* __restrict__ Qhi, unsigned short* __restrict__ Qlo,
    unsigned short* __restrict__ Khi, unsigned short* __restrict__ Klo,
    unsigned short* __restrict__ Vt)
{
    __shared__ __align__(16) unsigned short Ah[128 * 32];
    __shared__ __align__(16) unsigned short Al[128 * 32];
    __shared__ __align__(16) unsigned short Bh[128 * 32];
    __shared__ __align__(16) unsigned short Bl[128 * 32];

    const int tid  = threadIdx.x;
    const int lane = tid & 63, w = tid >> 6;
    const int wr = w >> 1, wc = w & 1;
    const int lr = lane & 15, kg = lane >> 4;
    const int row0 = blockIdx.x * 128;              // global over [0, 3M)
    const int col0 = blockIdx.y * 128;
    const int sel  = row0 >> 12;                    // 0=Q 1=K 2=V

    const unsigned short* Bhi =
        (sel == 0) ? WQt_hi : (sel == 1) ? WKt_hi : WVt_hi;
    const unsigned short* Blo = Bhi + (size_t)CC * CC;
    const float* bias = (sel == 0) ? bQ : (sel == 1) ? bK : bV;
    const float scale = (sel == 0) ? 0.125f * LOG2E : 1.0f;

    f32x4 acc[4][4];
    #pragma unroll
    for (int i = 0; i < 4; ++i)
        #pragma unroll
        for (int j = 0; j < 4; ++j)
            acc[i][j] = (f32x4){0.f, 0.f, 0.f, 0.f};

    const int srow = lane >> 2;
    const int ssl  = ((lane & 3) ^ ((srow >> 1) & 3)) * 8;
    const int ko   = (kg ^ ((lr >> 1) & 3)) * 8;

    const int NT = CC / 32;
    for (int kt = 0; kt < NT; ++kt) {
        const int k0 = kt * 32;
        #pragma unroll
        for (int c = 0; c < 2; ++c) {
            const int chunk = w * 2 + c;
            const int r = chunk * 16 + srow;
            GLOAD_LDS16(Ahi + (size_t)(row0 + r) * CC + k0 + ssl, &Ah[chunk * 512]);
            GLOAD_LDS16(Alo + (size_t)(row0 + r) * CC + k0 + ssl, &Al[chunk * 512]);
            GLOAD_LDS16(Bhi + (size_t)(col0 + r) * CC + k0 + ssl, &Bh[chunk * 512]);
            GLOAD_LDS16(Blo + (size_t)(col0 + r) * CC + k0 + ssl, &Bl[chunk * 512]);
        }
        __syncthreads();

        bf16x8 ah[4], al[4], bh[4], bl[4];
        #pragma unroll
        for (int i = 0; i < 4; ++i) {
            ah[i] = *(const bf16x8*)&Ah[(wr * 64 + i * 16 + lr) * 32 + ko];
            al[i] = *(const bf16x8*)&Al[(wr * 64 + i * 16 + lr) * 32 + ko];
            bh[i] = *(const bf16x8*)&Bh[(wc * 64 + i * 16 + lr) * 32 + ko];
            bl[i] = *(const bf16x8*)&Bl[(wc * 64 + i * 16 + lr) * 32 + ko];
        }
        #pragma unroll
        for (int i = 0; i < 4; ++i)
            #pragma unroll
            for (int j = 0; j < 4; ++j) {
                acc[i][j] = MFMA16(ah[i], bh[j], acc[i][j]);
                acc[i][j] = MFMA16(ah[i], bl[j], acc[i][j]);
                acc[i][j] = MFMA16(al[i], bh[j], acc[i][j]);
            }
        __syncthreads();
    }

    #pragma unroll
    for (int j = 0; j < 4; ++j) {
        const int n = col0 + wc * 64 + j * 16 + lr;
        const float bv = bias[n];
        const int hh = n >> 6, dd = n & 63;
        #pragma unroll
        for (int i = 0; i < 4; ++i) {
            const int mbase = row0 + wr * 64 + i * 16 + kg * 4;
            #pragma unroll
            for (int r = 0; r < 4; ++r) {
                const float v = (acc[i][j][r] + bv) * scale;
                const int ml = (mbase + r) & (MM - 1);       // row within [M]
                const int bb = ml >> 11, ll = ml & (LL - 1);
                if (sel == 2) {
                    Vt[((size_t)(bb * HH + hh) * DD + dd) * LL + ll] = f2bf(v);
                } else {
                    const size_t o = ((size_t)(bb * HH + hh) * LL + ll) * DD + dd;
                    unsigned short hi, lo;
                    split2(v, hi, lo);
                    if (sel == 0) { Qhi[o] = hi; Qlo[o] = lo; }
                    else          { Khi[o] = hi; Klo[o] = lo; }
                }
            }
        }
    }
}

// ---------------------------------------------------------------------------
// O-projection GEMM: BM=64 tile -> 512 blocks = 2 blocks/CU.
// Y[M][C] f32 = A[M,K] @ Bt[N,K]^T + bias (3-product split).
// ---------------------------------------------------------------------------
__global__ __launch_bounds__(256) void o_gemm(
    const unsigned short* __restrict__ Ahi, const unsigned short* __restrict__ Alo,
    const unsigned short* __restrict__ Bhi, const unsigned short* __restrict__ Blo,
    const float* __restrict__ bias, float* __restrict__ Yf)
{
    __shared__ __align__(16) unsigned short Ah[64 * 32];
    __shared__ __align__(16) unsigned short Al[64 * 32];
    __shared__ __align__(16) unsigned short Bh[128 * 32];
    __shared__ __align__(16) unsigned short Bl[128 * 32];

    const int tid  = threadIdx.x;
    const int lane = tid & 63, w = tid >> 6;
    const int wr = w >> 1, wc = w & 1;
    const int lr = lane & 15, kg = lane >> 4;
    const int row0 = blockIdx.x * 64, col0 = blockIdx.y * 128;

    f32x4 acc[2][4];
    #pragma unroll
    for (int i = 0; i < 2; ++i)
        #pragma unroll
        for (int j = 0; j < 4; ++j)
            acc[i][j] = (f32x4){0.f, 0.f, 0.f, 0.f};

    const int srow = lane >> 2;
    const int ssl  = ((lane & 3) ^ ((srow >> 1) & 3)) * 8;
    const int ko   = (kg ^ ((lr >> 1) & 3)) * 8;

    const int NT = CC / 32;
    for (int kt = 0; kt < NT; ++kt) {
        const int k0 = kt * 32;
        {   // A: 4 chunks of 16 rows, one per wave
            const int r = w * 16 + srow;
            GLOAD_LDS16(Ahi + (size_t)(row0 + r) * CC + k0 + ssl, &Ah[w * 512]);
            GLOAD_LDS16(Alo + (size_t)(row0 + r) * CC + k0 + ssl, &Al[w * 512]);
        }
        #pragma unroll
        for (int c = 0; c < 2; ++c) {   // B: 8 chunks
            const int chunk = w * 2 + c;
            const int r = chunk * 16 + srow;
            GLOAD_LDS16(Bhi + (size_t)(col0 + r) * CC + k0 + ssl, &Bh[chunk * 512]);
            GLOAD_LDS16(Blo + (size_t)(col0 + r) * CC + k0 + ssl, &Bl[chunk * 512]);
        }
        __syncthreads();

        bf16x8 ah[2], al[2], bh[4], bl[4];
        #pragma unroll
        for (int i = 0; i < 2; ++i) {
            ah[i] = *(const bf16x8*)&Ah[(wr * 32 + i * 16 + lr) * 32 + ko];
            al[i] = *(const bf16x8*)&Al[(wr * 32 + i * 16 + lr) * 32 + ko];
        }
        #pragma unroll
        for (int j = 0; j < 4; ++j) {
            bh[j] = *(const bf16x8*)&Bh[(wc * 64 + j * 16 + lr) * 32 + ko];
            bl[j] = *(const bf16x8*)&Bl[(wc * 64 + j * 16 + lr) * 32 + ko];
        }
        #pragma unroll
        for (int i = 0; i < 2; ++i)
            #pragma unroll
            for (int j = 0; j < 4; ++j) {
                acc[i][j] = MFMA16(ah[i], bh[j], acc[i][j]);
                acc[i][j] = MFMA16(ah[i], bl[j], acc[i][j]);
                acc[i][j] = MFMA16(al[i], bh[j], acc[i][j]);
            }
        __syncthreads();
    }

    #pragma unroll
    for (int j = 0; j < 4; ++j) {
        const int n = col0 + wc * 64 + j * 16 + lr;
        const float bv = bias[n];
        #pragma unroll
        for (int i = 0; i < 2; ++i) {
            const int mbase = row0 + wr * 32 + i * 16 + kg * 4;
            #pragma unroll
            for (int r = 0; r < 4; ++r)
                Yf[(size_t)(mbase + r) * CC + n] = acc[i][j][r] + bv;
        }
    }
}

// ---------------------------------------------------------------------------
// flash attention — unchanged from round 10 (verified 155.7 us).
// ---------------------------------------------------------------------------
__global__ __launch_bounds__(256) void flash_mfma(
    const unsigned short* __restrict__ Qhi, const unsigned short* __restrict__ Qlo,
    const unsigned short* __restrict__ Khi, const unsigned short* __restrict__ Klo,
    const unsigned short* __restrict__ Vt,  const unsigned int* __restrict__ maskp,
    unsigned short* __restrict__ Zhi, unsigned short* __restrict__ Zlo)
{
    __shared__ __align__(16) unsigned short Kh_s[64 * 64];
    __shared__ __align__(16) unsigned short Kl_s[64 * 64];
    __shared__ __align__(16) unsigned short Vt_s[64 * 64];
    __shared__ __align__(16) __bf16 Ps[4][16 * 72];

    const int tid  = threadIdx.x;
    const int lane = tid & 63, w = tid >> 6;
    const int lr = lane & 15, kg = lane >> 4;
    const int q0 = blockIdx.x * 64;
    const int h = blockIdx.y, b = blockIdx.z;
    const size_t bh = (size_t)(b * HH + h);

    const unsigned short* Qhi_b = Qhi + bh * LL * DD;
    const unsigned short* Qlo_b = Qlo + bh * LL * DD;
    const unsigned short* Khi_b = Khi + bh * LL * DD;
    const unsigned short* Klo_b = Klo + bh * LL * DD;
    const unsigned short* Vt_b  = Vt  + bh * DD * LL;

    const int qrow = q0 + w * 16 + lr;
    bf16x8 qh[2], ql[2];
    #pragma unroll
    for (int s = 0; s < 2; ++s) {
        qh[s] = *(const bf16x8*)&Qhi_b[(size_t)qrow * DD + s * 32 + kg * 8];
        ql[s] = *(const bf16x8*)&Qlo_b[(size_t)qrow * DD + s * 32 + kg * 8];
    }

    f32x4 oacc[4];
    float m_r[4], l_r[4];
    #pragma unroll
    for (int r = 0; r < 4; ++r) {
        oacc[r] = (f32x4){0.f, 0.f, 0.f, 0.f};
        m_r[r] = -3.0e38f; l_r[r] = 0.f;
    }

    const int NT = LL / 64;
    for (int kt = 0; kt < NT; ++kt) {
        #pragma unroll
        for (int c = 0; c < 2; ++c) {
            const int chunk = w * 2 + c;
            const int rowi = chunk * 8 + (lane >> 3);
            const int cb   = (lane & 7) * 16;
            const int scb  = cb ^ ((rowi & 7) << 4);
            GLOAD_LDS16(Khi_b + (size_t)(kt * 64 + rowi) * DD + scb / 2, &Kh_s[chunk * 512]);
            GLOAD_LDS16(Klo_b + (size_t)(kt * 64 + rowi) * DD + scb / 2, &Kl_s[chunk * 512]);
            GLOAD_LDS16(Vt_b + (size_t)rowi * LL + kt * 64 + scb / 2,    &Vt_s[chunk * 512]);
        }
        __syncthreads();

        f32x4 sacc[4];
        #pragma unroll
        for (int j = 0; j < 4; ++j) sacc[j] = (f32x4){0.f, 0.f, 0.f, 0.f};
        __builtin_amdgcn_s_setprio(1);
        #pragma unroll
        for (int j = 0; j < 4; ++j) {
            const int krow = j * 16 + lr;
            const int rswz = (krow & 7) << 4;
            #pragma unroll
            for (int s = 0; s < 2; ++s) {
                const int cb = (s * 64 + kg * 16) ^ rswz;
                bf16x8 kh = *(const bf16x8*)((const char*)&Kh_s[0] + krow * 128 + cb);
                bf16x8 kl = *(const bf16x8*)((const char*)&Kl_s[0] + krow * 128 + cb);
                sacc[j] = MFMA16(qh[s], kh, sacc[j]);
                sacc[j] = MFMA16(qh[s], kl, sacc[j]);
                sacc[j] = MFMA16(ql[s], kh, sacc[j]);
            }
        }
        __builtin_amdgcn_s_setprio(0);

        float mxr[4];
        #pragma unroll
        for (int r = 0; r < 4; ++r) {
            const int qr = q0 + w * 16 + kg * 4 + r;
            const unsigned int* mb = maskp + ((size_t)b * LL + qr) * (LL / 32) + kt * 2;
            const unsigned int m0 = mb[0], m1 = mb[1];
            float mx = -3.0e38f;
            #pragma unroll
            for (int j = 0; j < 4; ++j) {
                const unsigned int wsel = (j < 2) ? m0 : m1;
                const int bit = (j & 1) * 16 + lr;
                if (((wsel >> bit) & 1u) == 0u) sacc[j][r] = -1.0e9f;
                mx = fmaxf(mx, sacc[j][r]);
            }
            #pragma unroll
            for (int off = 1; off < 16; off <<= 1)
                mx = fmaxf(mx, __shfl_xor(mx, off, 16));
            mxr[r] = mx;
        }

        const float g = fmaxf(fmaxf(mxr[0] - m_r[0], mxr[1] - m_r[1]),
                              fmaxf(mxr[2] - m_r[2], mxr[3] - m_r[3]));
        if (!__all(g <= 8.0f)) {
            #pragma unroll
            for (int r = 0; r < 4; ++r) {
                const float mnew = fmaxf(m_r[r], mxr[r]);
                const float f = EXP2F(m_r[r] - mnew);
                m_r[r] = mnew;
                l_r[r] *= f;
                #pragma unroll
                for (int jd = 0; jd < 4; ++jd) oacc[jd][r] *= f;
            }
        }

        #pragma unroll
        for (int r = 0; r < 4; ++r) {
            float sum = 0.f;
            #pragma unroll
            for (int j = 0; j < 4; ++j) {
                const float p = EXP2F(sacc[j][r] - m_r[r]);
                sum += p;
                Ps[w][(kg * 4 + r) * 72 + j * 16 + lr] = (__bf16)p;
            }
            #pragma unroll
            for (int off = 1; off < 16; off <<= 1)
                sum += __shfl_xor(sum, off, 16);
            l_r[r] += sum;
        }

        __builtin_amdgcn_s_setprio(1);
        #pragma unroll
        for (int s = 0; s < 2; ++s) {
            bf16x8 pa = *(const bf16x8*)&Ps[w][lr * 72 + s * 32 + kg * 8];
            #pragma unroll
            for (int jd = 0; jd < 4; ++jd) {
                const int vrow = jd * 16 + lr;
                const int cb = (s * 64 + kg * 16) ^ ((vrow & 7) << 4);
                bf16x8 vb = *(const bf16x8*)((const char*)&Vt_s[0] + vrow * 128 + cb);
                oacc[jd] = MFMA16(pa, vb, oacc[jd]);
            }
        }
        __builtin_amdgcn_s_setprio(0);
        __syncthreads();
    }

    #pragma unroll
    for (int r = 0; r < 4; ++r) {
        const float inv = 1.0f / l_r[r];
        const int qg = q0 + w * 16 + kg * 4 + r;
        const size_t rowb = ((size_t)(b * LL + qg)) * CC + h * DD;
        #pragma unroll
        for (int jd = 0; jd < 4; ++jd) {
            unsigned short hi, lo;
            split2(oacc[jd][r] * inv, hi, lo);
            Zhi[rowb + jd * 16 + lr] = hi;
            Zlo[rowb + jd * 16 + lr] = lo;
        }
    }
}

// ---------------------------------------------------------------------------
extern "C" void kernel_launch(void* const* d_in, const int* in_sizes, int n_in,
                              void* d_out, int out_size, void* d_ws, size_t ws_size,
                              hipStream_t stream)
{
    const float* query = (const float*)d_in[0];
    const float* key   = (const float*)d_in[1];
    const float* value = (const float*)d_in[2];
    const int*   mask  = (const int*)d_in[3];
    const float* WQ = (const float*)d_in[4];
    const float* bQ = (const float*)d_in[5];
    const float* WK = (const float*)d_in[6];
    const float* bK = (const float*)d_in[7];
    const float* WV = (const float*)d_in[8];
    const float* bV = (const float*)d_in[9];
    const float* WO = (const float*)d_in[10];
    const float* bO = (const float*)d_in[11];
    float* out = (float*)d_out;

    char* ws = (char*)d_ws;
    const size_t MB = 1024 * 1024;
    // weights (hi at z*4MB, lo at +2MB)
    unsigned short* WQt_hi = (unsigned short*)(ws + 0 * MB);
    unsigned short* WKt_hi = (unsigned short*)(ws + 4 * MB);
    unsigned short* WVt_hi = (unsigned short*)(ws + 8 * MB);
    unsigned short* WOt_hi = (unsigned short*)(ws + 12 * MB);
    unsigned short* WOt_lo = (unsigned short*)(ws + 14 * MB);
    unsigned short* Xall_hi = (unsigned short*)(ws + 16 * MB);  // [3M][C] 24MB
    unsigned short* Xall_lo = (unsigned short*)(ws + 40 * MB);  // 24MB
    unsigned short* Qh_hi  = (unsigned short*)(ws + 64 * MB);
    unsigned short* Qh_lo  = (unsigned short*)(ws + 72 * MB);
    unsigned short* Kh_hi  = (unsigned short*)(ws + 80 * MB);
    unsigned short* Kh_lo  = (unsigned short*)(ws + 88 * MB);
    unsigned short* Vt     = (unsigned short*)(ws + 96 * MB);   // 8MB
    unsigned int*   maskp  = (unsigned int*)(ws + 104 * MB);    // 2MB -> 106 total
    // flash output reuses dead Xall_hi region
    unsigned short* Zh_hi  = (unsigned short*)(ws + 16 * MB);
    unsigned short* Zh_lo  = (unsigned short*)(ws + 24 * MB);

    const dim3 blk(256);
    w_prep4<<<dim3(CC / 64, CC / 64, 4), blk, 0, stream>>>(WQ, WK, WV, WO, ws);
    mask_pack<<<dim3((BB * LL * (LL / 32)) / 256), blk, 0, stream>>>(mask, maskp);
    x_prep3<<<dim3((size_t)MM * CC / 4 / 256, 3), blk, 0, stream>>>(
        query, key, value, Xall_hi, Xall_lo);

    // batched Q/K/V projections: 96x8 = 768 blocks = 3 blocks/CU
    qkv_gemm<<<dim3(3 * MM / 128, CC / 128), blk, 0, stream>>>(
        Xall_hi, Xall_lo, WQt_hi, WKt_hi, WVt_hi, bQ, bK, bV,
        Qh_hi, Qh_lo, Kh_hi, Kh_lo, Vt);

    flash_mfma<<<dim3(LL / 64, HH, BB), blk, 0, stream>>>(
        Qh_hi, Qh_lo, Kh_hi, Kh_lo, Vt, maskp, Zh_hi, Zh_lo);

    // out = Zh @ WO + bO : 64x8 -> 512 blocks = 2 blocks/CU
    o_gemm<<<dim3(MM / 64, CC / 128), blk, 0, stream>>>(
        Zh_hi, Zh_lo, WOt_hi, WOt_lo, bO, out);
}